// Round 2
// baseline (1871.098 us; speedup 1.0000x reference)
//
#include <hip/hip_runtime.h>

// B=8, L=2048, D=512, H=512, E=256, K=30.  All float tensors fp32, x_lengths int32.
// Key identity: softmax -> key-mask -> renorm -> top-30 -> renorm  ==
//   softmax over the 30 largest raw logits among valid keys (len >= 1024 >> 30).

// ---------------------------------------------------------------------------
// k1: fused projection GEMM.  [x_prime | x1 | x2](m, :) = x[m,:] @ [w_g|t1|t2] + bias
// 16 rows per block, 256 threads, thread tile = 4 rows x 16 cols.
// ---------------------------------------------------------------------------
__global__ __launch_bounds__(256) void k1_proj(
    const float* __restrict__ x,
    const float* __restrict__ wg, const float* __restrict__ bg,
    const float* __restrict__ w1, const float* __restrict__ b1,
    const float* __restrict__ w2, const float* __restrict__ b2,
    float* __restrict__ xp, float* __restrict__ x1o, float* __restrict__ x2o)
{
    __shared__ float xs[16][512];
    const int t = threadIdx.x;
    const int m0 = blockIdx.x * 16;

    #pragma unroll
    for (int q = 0; q < 8; ++q) {                 // 16x512 fp32 tile -> LDS (32 KB)
        int f = t * 4 + 1024 * q;
        int r = f >> 9, k = f & 511;
        *(float4*)&xs[r][k] = *(const float4*)(x + (size_t)(m0 + r) * 512 + k);
    }
    __syncthreads();

    const int rg = t >> 6, ct = t & 63;
    const int r0 = rg * 4;

    float acc[4][16];
    #pragma unroll
    for (int i = 0; i < 4; ++i)
        #pragma unroll
        for (int c = 0; c < 16; ++c) acc[i][c] = 0.f;

    const float* wp[4];
    int wstr[4];
    wp[0] = wg + ct * 4;        wstr[0] = 512;    // cols [0,256)   -> x_prime
    wp[1] = wg + 256 + ct * 4;  wstr[1] = 512;    // cols [256,512) -> x_prime
    wp[2] = w1 + ct * 4;        wstr[2] = 256;    // -> x1
    wp[3] = w2 + ct * 4;        wstr[3] = 256;    // -> x2

    for (int k = 0; k < 512; ++k) {
        float xv[4];
        #pragma unroll
        for (int i = 0; i < 4; ++i) xv[i] = xs[r0 + i][k];   // LDS broadcast
        #pragma unroll
        for (int p = 0; p < 4; ++p) {
            float4 u = *(const float4*)wp[p];
            wp[p] += wstr[p];
            #pragma unroll
            for (int i = 0; i < 4; ++i) {
                acc[i][p * 4 + 0] = fmaf(xv[i], u.x, acc[i][p * 4 + 0]);
                acc[i][p * 4 + 1] = fmaf(xv[i], u.y, acc[i][p * 4 + 1]);
                acc[i][p * 4 + 2] = fmaf(xv[i], u.z, acc[i][p * 4 + 2]);
                acc[i][p * 4 + 3] = fmaf(xv[i], u.w, acc[i][p * 4 + 3]);
            }
        }
    }

    float4 ub[4];
    ub[0] = *(const float4*)(bg + ct * 4);
    ub[1] = *(const float4*)(bg + 256 + ct * 4);
    ub[2] = *(const float4*)(b1 + ct * 4);
    ub[3] = *(const float4*)(b2 + ct * 4);

    #pragma unroll
    for (int p = 0; p < 4; ++p) {
        float* dbase; size_t dstr; int col;
        if (p == 0)      { dbase = xp;  dstr = 512; col = ct * 4; }
        else if (p == 1) { dbase = xp;  dstr = 512; col = 256 + ct * 4; }
        else if (p == 2) { dbase = x1o; dstr = 256; col = ct * 4; }
        else             { dbase = x2o; dstr = 256; col = ct * 4; }
        #pragma unroll
        for (int i = 0; i < 4; ++i) {
            float4 o;
            o.x = acc[i][p * 4 + 0] + ub[p].x;
            o.y = acc[i][p * 4 + 1] + ub[p].y;
            o.z = acc[i][p * 4 + 2] + ub[p].z;
            o.w = acc[i][p * 4 + 3] + ub[p].w;
            *(float4*)(dbase + (size_t)(m0 + r0 + i) * dstr + col) = o;
        }
    }
}

// ---------------------------------------------------------------------------
// k2: per 8 query rows: scores vs all 2048 keys (E=256), key-length mask,
// top-30 via repeated wave-argmax over register-resident slices, softmax-30,
// gather-weighted sum of x_prime rows.
// ---------------------------------------------------------------------------
__global__ __launch_bounds__(256) void k2_attn(
    const float* __restrict__ x1, const float* __restrict__ x2,
    const float* __restrict__ xp, const int* __restrict__ xlen,
    float* __restrict__ ya)
{
    __shared__ float x1s[8][256];    //  8 KB
    __shared__ float sc[8][2048];    // 64 KB
    __shared__ float tkv[8][30];
    __shared__ int   tki[8][30];

    const int t = threadIdx.x;
    const int b = blockIdx.x >> 8;            // 256 row-blocks per batch
    const int i0 = (blockIdx.x & 255) * 8;
    const int len = xlen[b];
    const float* x1b = x1 + ((size_t)b * 2048 + i0) * 256;
    const float* x2b = x2 + (size_t)b * 2048 * 256;

    #pragma unroll
    for (int q = 0; q < 2; ++q) {             // 8x256 fp32 -> LDS
        int f = t * 4 + 1024 * q;
        *(float4*)&x1s[0][f] = *(const float4*)(x1b + f);
    }
    __syncthreads();

    // ---- scores: thread handles 4 consecutive keys x 8 rows, two passes ----
    for (int p = 0; p < 2; ++p) {
        const int j0 = t * 4 + p * 1024;
        const float* rp = x2b + (size_t)j0 * 256;
        float acc[8][4];
        #pragma unroll
        for (int r = 0; r < 8; ++r) { acc[r][0] = acc[r][1] = acc[r][2] = acc[r][3] = 0.f; }

        for (int e = 0; e < 256; e += 4) {
            float4 xv[8];
            #pragma unroll
            for (int r = 0; r < 8; ++r) xv[r] = *(const float4*)&x1s[r][e];  // broadcast
            #pragma unroll
            for (int jj = 0; jj < 4; ++jj) {
                float4 u = *(const float4*)(rp + jj * 256 + e);
                #pragma unroll
                for (int r = 0; r < 8; ++r) {
                    float a = acc[r][jj];
                    a = fmaf(xv[r].x, u.x, a);
                    a = fmaf(xv[r].y, u.y, a);
                    a = fmaf(xv[r].z, u.z, a);
                    a = fmaf(xv[r].w, u.w, a);
                    acc[r][jj] = a;
                }
            }
        }
        #pragma unroll
        for (int r = 0; r < 8; ++r) {
            float4 v;
            v.x = (j0 + 0 < len) ? acc[r][0] : -3e38f;
            v.y = (j0 + 1 < len) ? acc[r][1] : -3e38f;
            v.z = (j0 + 2 < len) ? acc[r][2] : -3e38f;
            v.w = (j0 + 3 < len) ? acc[r][3] : -3e38f;
            *(float4*)&sc[r][j0] = v;
        }
    }
    __syncthreads();

    // ---- top-30 per row: wave w owns rows 2w, 2w+1 ----
    const int lane = t & 63, wid = t >> 6;
    for (int rr = 0; rr < 2; ++rr) {
        const int r = wid * 2 + rr;
        float svv[32];                         // lane's j = lane*4 + c*256 + i
        #pragma unroll
        for (int c = 0; c < 8; ++c) {
            float4 v = *(const float4*)&sc[r][lane * 4 + c * 256];
            svv[c * 4 + 0] = v.x; svv[c * 4 + 1] = v.y;
            svv[c * 4 + 2] = v.z; svv[c * 4 + 3] = v.w;
        }
        for (int it = 0; it < 30; ++it) {
            float bv = -3.4e38f; int bq = 0;
            #pragma unroll
            for (int q = 0; q < 32; ++q) if (svv[q] > bv) { bv = svv[q]; bq = q; }
            int bj = lane * 4 + (bq >> 2) * 256 + (bq & 3);
            #pragma unroll
            for (int off = 32; off > 0; off >>= 1) {      // wave64 butterfly argmax
                float ov = __shfl_xor(bv, off);
                int   oj = __shfl_xor(bj, off);
                if (ov > bv || (ov == bv && oj < bj)) { bv = ov; bj = oj; }
            }
            if (lane == 0) { tkv[r][it] = bv; tki[r][it] = bj; }
            const int jl = (bj >> 2) & 63;
            const int myq = (jl == lane) ? (((bj >> 8) << 2) | (bj & 3)) : -1;
            #pragma unroll
            for (int q = 0; q < 32; ++q) if (q == myq) svv[q] = -3.4e38f;  // static idx
        }
    }
    __syncthreads();

    // ---- softmax over 30 + gather-weighted sum of x_prime rows ----
    const size_t mrow0 = (size_t)b * 2048 + i0;
    const int h0 = t * 2;
    for (int r = 0; r < 8; ++r) {
        const float v0 = tkv[r][0];            // iteration-0 argmax == row max
        float wvv[30]; float s = 0.f;
        #pragma unroll
        for (int k = 0; k < 30; ++k) { wvv[k] = __expf(tkv[r][k] - v0); s += wvv[k]; }
        const float inv = 1.f / s;
        float y0 = 0.f, y1 = 0.f;
        #pragma unroll
        for (int k = 0; k < 30; ++k) {
            int j = tki[r][k];
            float2 u = *(const float2*)(xp + ((size_t)b * 2048 + j) * 512 + h0);
            y0 = fmaf(wvv[k], u.x, y0);
            y1 = fmaf(wvv[k], u.y, y1);
        }
        float2 o; o.x = y0 * inv; o.y = y1 * inv;
        *(float2*)(ya + (mrow0 + r) * 512 + h0) = o;
    }
}

// ---------------------------------------------------------------------------
// k3: out = x + y_att @ w_z + b_z.  16 rows/block, thread tile 4x8.
// ---------------------------------------------------------------------------
__global__ __launch_bounds__(256) void k3_out(
    const float* __restrict__ ya, const float* __restrict__ wz,
    const float* __restrict__ bz, const float* __restrict__ x,
    float* __restrict__ out)
{
    __shared__ float ys[16][512];
    const int t = threadIdx.x;
    const int m0 = blockIdx.x * 16;

    #pragma unroll
    for (int q = 0; q < 8; ++q) {
        int f = t * 4 + 1024 * q;
        int r = f >> 9, k = f & 511;
        *(float4*)&ys[r][k] = *(const float4*)(ya + (size_t)(m0 + r) * 512 + k);
    }
    __syncthreads();

    const int rg = t >> 6, ct = t & 63;
    const int r0 = rg * 4;

    float acc[4][8];
    #pragma unroll
    for (int i = 0; i < 4; ++i)
        #pragma unroll
        for (int c = 0; c < 8; ++c) acc[i][c] = 0.f;

    const float* wp0 = wz + ct * 4;
    const float* wp1 = wz + 256 + ct * 4;

    for (int k = 0; k < 512; ++k) {
        float xv[4];
        #pragma unroll
        for (int i = 0; i < 4; ++i) xv[i] = ys[r0 + i][k];
        float4 u0 = *(const float4*)wp0; wp0 += 512;
        float4 u1 = *(const float4*)wp1; wp1 += 512;
        #pragma unroll
        for (int i = 0; i < 4; ++i) {
            acc[i][0] = fmaf(xv[i], u0.x, acc[i][0]);
            acc[i][1] = fmaf(xv[i], u0.y, acc[i][1]);
            acc[i][2] = fmaf(xv[i], u0.z, acc[i][2]);
            acc[i][3] = fmaf(xv[i], u0.w, acc[i][3]);
            acc[i][4] = fmaf(xv[i], u1.x, acc[i][4]);
            acc[i][5] = fmaf(xv[i], u1.y, acc[i][5]);
            acc[i][6] = fmaf(xv[i], u1.z, acc[i][6]);
            acc[i][7] = fmaf(xv[i], u1.w, acc[i][7]);
        }
    }

    float4 ub0 = *(const float4*)(bz + ct * 4);
    float4 ub1 = *(const float4*)(bz + 256 + ct * 4);
    float bb[8] = { ub0.x, ub0.y, ub0.z, ub0.w, ub1.x, ub1.y, ub1.z, ub1.w };

    #pragma unroll
    for (int i = 0; i < 4; ++i) {
        size_t mrow = (size_t)(m0 + r0 + i);
        #pragma unroll
        for (int p = 0; p < 2; ++p) {
            int n = ct * 4 + 256 * p;
            float4 xu = *(const float4*)(x + mrow * 512 + n);
            float4 o;
            o.x = acc[i][p * 4 + 0] + bb[p * 4 + 0] + xu.x;
            o.y = acc[i][p * 4 + 1] + bb[p * 4 + 1] + xu.y;
            o.z = acc[i][p * 4 + 2] + bb[p * 4 + 2] + xu.z;
            o.w = acc[i][p * 4 + 3] + bb[p * 4 + 3] + xu.w;
            *(float4*)(out + mrow * 512 + n) = o;
        }
    }
}

extern "C" void kernel_launch(void* const* d_in, const int* in_sizes, int n_in,
                              void* d_out, int out_size, void* d_ws, size_t ws_size,
                              hipStream_t stream)
{
    (void)in_sizes; (void)n_in; (void)out_size; (void)ws_size;

    const float* x   = (const float*)d_in[0];
    const float* wg  = (const float*)d_in[1];
    const float* bg  = (const float*)d_in[2];
    const float* w1  = (const float*)d_in[3];
    const float* b1  = (const float*)d_in[4];
    const float* w2  = (const float*)d_in[5];
    const float* b2  = (const float*)d_in[6];
    const float* wzw = (const float*)d_in[7];
    const float* wzb = (const float*)d_in[8];
    const int* xlen  = (const int*)d_in[9];
    float* outp      = (float*)d_out;

    char* ws = (char*)d_ws;
    float* x1w = (float*)(ws);                        // 16 MiB [16384,256] fp32
    float* x2w = (float*)(ws + 16u * 1024 * 1024);    // 16 MiB [16384,256] fp32
    float* xpw = (float*)(ws + 32u * 1024 * 1024);    // 32 MiB [16384,512] fp32
    float* yaw = (float*)(ws + 64u * 1024 * 1024);    // 32 MiB [16384,512] fp32

    hipLaunchKernelGGL(k1_proj, dim3(1024), dim3(256), 0, stream,
                       x, wg, bg, w1, b1, w2, b2, xpw, x1w, x2w);
    hipLaunchKernelGGL(k2_attn, dim3(2048), dim3(256), 0, stream,
                       x1w, x2w, xpw, xlen, yaw);
    hipLaunchKernelGGL(k3_out, dim3(1024), dim3(256), 0, stream,
                       yaw, wzw, wzb, x, outp);
}

// Round 3
// 1098.493 us; speedup vs baseline: 1.7033x; 1.7033x over previous
//
#include <hip/hip_runtime.h>

// B=8, L=2048, D=512, H=512, E=256, K=30.  fp32 everywhere, x_lengths int32.
// Identity: softmax -> key-mask -> renorm -> top-30 -> renorm ==
//   softmax over the 30 largest raw logits among valid keys (len >= 1024 >> 30).

// ---------------------------------------------------------------------------
// k1: fused projection GEMM.  x_prime = x@wg+bg, x1 = x@t1+b1, x2T = (x@t2+b2)^T
// 16 rows per block, 256 threads, thread tile = 4 rows x 16 cols.
// x2 is written TRANSPOSED (x2T[b][e][key]) via an LDS round-trip so k2's
// score loop reads consecutive keys (coalesced).
// ---------------------------------------------------------------------------
__global__ __launch_bounds__(256) void k1_proj(
    const float* __restrict__ x,
    const float* __restrict__ wg, const float* __restrict__ bg,
    const float* __restrict__ w1, const float* __restrict__ b1,
    const float* __restrict__ w2, const float* __restrict__ b2,
    float* __restrict__ xp, float* __restrict__ x1o, float* __restrict__ x2t)
{
    __shared__ float xs[16][512];                 // 32 KB; reused for transpose
    const int t = threadIdx.x;
    const int m0 = blockIdx.x * 16;

    #pragma unroll
    for (int q = 0; q < 8; ++q) {                 // 16x512 fp32 tile -> LDS
        int f = t * 4 + 1024 * q;
        int r = f >> 9, k = f & 511;
        *(float4*)&xs[r][k] = *(const float4*)(x + (size_t)(m0 + r) * 512 + k);
    }
    __syncthreads();

    const int rg = t >> 6, ct = t & 63;
    const int r0 = rg * 4;

    float acc[4][16];
    #pragma unroll
    for (int i = 0; i < 4; ++i)
        #pragma unroll
        for (int c = 0; c < 16; ++c) acc[i][c] = 0.f;

    const float* wp[4];
    int wstr[4];
    wp[0] = wg + ct * 4;        wstr[0] = 512;    // cols [0,256)   -> x_prime
    wp[1] = wg + 256 + ct * 4;  wstr[1] = 512;    // cols [256,512) -> x_prime
    wp[2] = w1 + ct * 4;        wstr[2] = 256;    // -> x1
    wp[3] = w2 + ct * 4;        wstr[3] = 256;    // -> x2 (transposed out)

    for (int k = 0; k < 512; ++k) {
        float xv[4];
        #pragma unroll
        for (int i = 0; i < 4; ++i) xv[i] = xs[r0 + i][k];   // LDS broadcast
        #pragma unroll
        for (int p = 0; p < 4; ++p) {
            float4 u = *(const float4*)wp[p];
            wp[p] += wstr[p];
            #pragma unroll
            for (int i = 0; i < 4; ++i) {
                acc[i][p * 4 + 0] = fmaf(xv[i], u.x, acc[i][p * 4 + 0]);
                acc[i][p * 4 + 1] = fmaf(xv[i], u.y, acc[i][p * 4 + 1]);
                acc[i][p * 4 + 2] = fmaf(xv[i], u.z, acc[i][p * 4 + 2]);
                acc[i][p * 4 + 3] = fmaf(xv[i], u.w, acc[i][p * 4 + 3]);
            }
        }
    }

    float4 ub[4];
    ub[0] = *(const float4*)(bg + ct * 4);
    ub[1] = *(const float4*)(bg + 256 + ct * 4);
    ub[2] = *(const float4*)(b1 + ct * 4);
    ub[3] = *(const float4*)(b2 + ct * 4);

    __syncthreads();                              // all waves done reading xs

    // p = 0,1 -> x_prime ; p = 2 -> x1 (row-major global stores)
    #pragma unroll
    for (int p = 0; p < 3; ++p) {
        float* dbase; size_t dstr; int col;
        if (p == 0)      { dbase = xp;  dstr = 512; col = ct * 4; }
        else if (p == 1) { dbase = xp;  dstr = 512; col = 256 + ct * 4; }
        else             { dbase = x1o; dstr = 256; col = ct * 4; }
        #pragma unroll
        for (int i = 0; i < 4; ++i) {
            float4 o;
            o.x = acc[i][p * 4 + 0] + ub[p].x;
            o.y = acc[i][p * 4 + 1] + ub[p].y;
            o.z = acc[i][p * 4 + 2] + ub[p].z;
            o.w = acc[i][p * 4 + 3] + ub[p].w;
            *(float4*)(dbase + (size_t)(m0 + r0 + i) * dstr + col) = o;
        }
    }

    // p = 3 -> x2: stash [16 rows][256 e] into LDS, then store transposed
    float* xs2 = &xs[0][0];                       // flat [16][256]
    #pragma unroll
    for (int i = 0; i < 4; ++i) {
        float4 o;
        o.x = acc[i][12] + ub[3].x;
        o.y = acc[i][13] + ub[3].y;
        o.z = acc[i][14] + ub[3].z;
        o.w = acc[i][15] + ub[3].w;
        *(float4*)(xs2 + (r0 + i) * 256 + ct * 4) = o;
    }
    __syncthreads();

    {
        const int e  = t;                          // 0..255
        const int b  = m0 >> 11;                   // batch
        const int j0 = m0 & 2047;                  // key offset within batch
        float* dst = x2t + ((size_t)b * 256 + e) * 2048 + j0;
        #pragma unroll
        for (int g = 0; g < 4; ++g) {
            float4 v;
            v.x = xs2[(g * 4 + 0) * 256 + e];      // conflict-free column read
            v.y = xs2[(g * 4 + 1) * 256 + e];
            v.z = xs2[(g * 4 + 2) * 256 + e];
            v.w = xs2[(g * 4 + 3) * 256 + e];
            *(float4*)(dst + g * 4) = v;
        }
    }
}

// ---------------------------------------------------------------------------
// k2: 512 threads, 16 query rows per block.  Wave w owns rows {2w, 2w+1}.
// Scores accumulate directly in the top-k register layout
// (key j = c*256 + lane*4 + i  <->  reg q = c*4+i), fed by coalesced x2T reads.
// Then: length mask, top-30 wave-argmax, softmax-30, gather of x_prime.
// ---------------------------------------------------------------------------
__global__ __launch_bounds__(512, 4) void k2_attn(
    const float* __restrict__ x1, const float* __restrict__ x2t,
    const float* __restrict__ xp, const int* __restrict__ xlen,
    float* __restrict__ ya)
{
    __shared__ float x1s[16][256];                // 16 KB
    __shared__ float tkv[16][30];
    __shared__ int   tki[16][30];

    const int t  = threadIdx.x;
    const int b  = blockIdx.x >> 7;               // 128 row-blocks per batch
    const int i0 = (blockIdx.x & 127) * 16;
    const int len = xlen[b];

    {   // 16x256 fp32 -> LDS, coalesced
        const float* x1b = x1 + ((size_t)b * 2048 + i0) * 256;
        #pragma unroll
        for (int q = 0; q < 2; ++q) {
            int f = t * 4 + 2048 * q;
            *(float4*)&x1s[0][f] = *(const float4*)(x1b + f);
        }
    }
    __syncthreads();

    const int lane = t & 63, wid = t >> 6;        // wid 0..7
    const int r0 = wid * 2;
    const int cbase = lane * 4;

    float a0[32], a1[32];
    #pragma unroll
    for (int q = 0; q < 32; ++q) { a0[q] = 0.f; a1[q] = 0.f; }

    // ---- scores: per e, 8 coalesced float4 key-chunks, 64 FMAs ----
    const float* x2tb = x2t + (size_t)b * 256 * 2048;
    for (int e = 0; e < 256; ++e) {
        const float* row = x2tb + (size_t)e * 2048 + cbase;
        const float xv0 = x1s[r0][e];             // LDS broadcast
        const float xv1 = x1s[r0 + 1][e];
        #pragma unroll
        for (int c = 0; c < 8; ++c) {
            float4 u = *(const float4*)(row + c * 256);
            a0[c*4+0] = fmaf(xv0, u.x, a0[c*4+0]);
            a0[c*4+1] = fmaf(xv0, u.y, a0[c*4+1]);
            a0[c*4+2] = fmaf(xv0, u.z, a0[c*4+2]);
            a0[c*4+3] = fmaf(xv0, u.w, a0[c*4+3]);
            a1[c*4+0] = fmaf(xv1, u.x, a1[c*4+0]);
            a1[c*4+1] = fmaf(xv1, u.y, a1[c*4+1]);
            a1[c*4+2] = fmaf(xv1, u.z, a1[c*4+2]);
            a1[c*4+3] = fmaf(xv1, u.w, a1[c*4+3]);
        }
    }

    // ---- key-length mask ----
    #pragma unroll
    for (int c = 0; c < 8; ++c)
        #pragma unroll
        for (int i = 0; i < 4; ++i) {
            int j = c * 256 + cbase + i;
            if (j >= len) { a0[c*4+i] = -3e38f; a1[c*4+i] = -3e38f; }
        }

    // ---- top-30 per row (wave-argmax, registers only) ----
#define TOPK_ROW(ARR, ROW)                                                  \
    for (int it = 0; it < 30; ++it) {                                       \
        float bv = -3.4e38f; int bq = 0;                                    \
        _Pragma("unroll")                                                   \
        for (int q = 0; q < 32; ++q) if (ARR[q] > bv) { bv = ARR[q]; bq = q; } \
        int bj = cbase + (bq >> 2) * 256 + (bq & 3);                        \
        _Pragma("unroll")                                                   \
        for (int off = 32; off > 0; off >>= 1) {                            \
            float ov = __shfl_xor(bv, off);                                 \
            int   oj = __shfl_xor(bj, off);                                 \
            if (ov > bv || (ov == bv && oj < bj)) { bv = ov; bj = oj; }     \
        }                                                                   \
        if (lane == 0) { tkv[ROW][it] = bv; tki[ROW][it] = bj; }            \
        const int jl = (bj >> 2) & 63;                                      \
        const int myq = (jl == lane) ? (((bj >> 8) << 2) | (bj & 3)) : -1;  \
        _Pragma("unroll")                                                   \
        for (int q = 0; q < 32; ++q) if (q == myq) ARR[q] = -3.4e38f;       \
    }

    TOPK_ROW(a0, r0)
    TOPK_ROW(a1, r0 + 1)
#undef TOPK_ROW
    __syncthreads();

    // ---- softmax over 30 + gather-weighted sum of x_prime rows ----
    const int g  = t >> 8;                        // 0..1 -> rows g*8..g*8+8
    const int h0 = (t & 255) * 2;
    for (int r = g * 8; r < g * 8 + 8; ++r) {
        const float v0 = tkv[r][0];               // iteration-0 argmax == max
        float wvv[30]; float s = 0.f;
        #pragma unroll
        for (int k = 0; k < 30; ++k) { wvv[k] = __expf(tkv[r][k] - v0); s += wvv[k]; }
        const float inv = 1.f / s;
        float y0 = 0.f, y1 = 0.f;
        #pragma unroll
        for (int k = 0; k < 30; ++k) {
            int j = tki[r][k];
            float2 u = *(const float2*)(xp + ((size_t)b * 2048 + j) * 512 + h0);
            y0 = fmaf(wvv[k], u.x, y0);
            y1 = fmaf(wvv[k], u.y, y1);
        }
        float2 o; o.x = y0 * inv; o.y = y1 * inv;
        *(float2*)(ya + ((size_t)b * 2048 + i0 + r) * 512 + h0) = o;
    }
}

// ---------------------------------------------------------------------------
// k3: out = x + y_att @ w_z + b_z.  16 rows/block, thread tile 4x8.
// ---------------------------------------------------------------------------
__global__ __launch_bounds__(256) void k3_out(
    const float* __restrict__ ya, const float* __restrict__ wz,
    const float* __restrict__ bz, const float* __restrict__ x,
    float* __restrict__ out)
{
    __shared__ float ys[16][512];
    const int t = threadIdx.x;
    const int m0 = blockIdx.x * 16;

    #pragma unroll
    for (int q = 0; q < 8; ++q) {
        int f = t * 4 + 1024 * q;
        int r = f >> 9, k = f & 511;
        *(float4*)&ys[r][k] = *(const float4*)(ya + (size_t)(m0 + r) * 512 + k);
    }
    __syncthreads();

    const int rg = t >> 6, ct = t & 63;
    const int r0 = rg * 4;

    float acc[4][8];
    #pragma unroll
    for (int i = 0; i < 4; ++i)
        #pragma unroll
        for (int c = 0; c < 8; ++c) acc[i][c] = 0.f;

    const float* wp0 = wz + ct * 4;
    const float* wp1 = wz + 256 + ct * 4;

    for (int k = 0; k < 512; ++k) {
        float xv[4];
        #pragma unroll
        for (int i = 0; i < 4; ++i) xv[i] = ys[r0 + i][k];
        float4 u0 = *(const float4*)wp0; wp0 += 512;
        float4 u1 = *(const float4*)wp1; wp1 += 512;
        #pragma unroll
        for (int i = 0; i < 4; ++i) {
            acc[i][0] = fmaf(xv[i], u0.x, acc[i][0]);
            acc[i][1] = fmaf(xv[i], u0.y, acc[i][1]);
            acc[i][2] = fmaf(xv[i], u0.z, acc[i][2]);
            acc[i][3] = fmaf(xv[i], u0.w, acc[i][3]);
            acc[i][4] = fmaf(xv[i], u1.x, acc[i][4]);
            acc[i][5] = fmaf(xv[i], u1.y, acc[i][5]);
            acc[i][6] = fmaf(xv[i], u1.z, acc[i][6]);
            acc[i][7] = fmaf(xv[i], u1.w, acc[i][7]);
        }
    }

    float4 ub0 = *(const float4*)(bz + ct * 4);
    float4 ub1 = *(const float4*)(bz + 256 + ct * 4);
    float bb[8] = { ub0.x, ub0.y, ub0.z, ub0.w, ub1.x, ub1.y, ub1.z, ub1.w };

    #pragma unroll
    for (int i = 0; i < 4; ++i) {
        size_t mrow = (size_t)(m0 + r0 + i);
        #pragma unroll
        for (int p = 0; p < 2; ++p) {
            int n = ct * 4 + 256 * p;
            float4 xu = *(const float4*)(x + mrow * 512 + n);
            float4 o;
            o.x = acc[i][p * 4 + 0] + bb[p * 4 + 0] + xu.x;
            o.y = acc[i][p * 4 + 1] + bb[p * 4 + 1] + xu.y;
            o.z = acc[i][p * 4 + 2] + bb[p * 4 + 2] + xu.z;
            o.w = acc[i][p * 4 + 3] + bb[p * 4 + 3] + xu.w;
            *(float4*)(out + mrow * 512 + n) = o;
        }
    }
}

extern "C" void kernel_launch(void* const* d_in, const int* in_sizes, int n_in,
                              void* d_out, int out_size, void* d_ws, size_t ws_size,
                              hipStream_t stream)
{
    (void)in_sizes; (void)n_in; (void)out_size; (void)ws_size;

    const float* x   = (const float*)d_in[0];
    const float* wg  = (const float*)d_in[1];
    const float* bg  = (const float*)d_in[2];
    const float* w1  = (const float*)d_in[3];
    const float* b1  = (const float*)d_in[4];
    const float* w2  = (const float*)d_in[5];
    const float* b2  = (const float*)d_in[6];
    const float* wzw = (const float*)d_in[7];
    const float* wzb = (const float*)d_in[8];
    const int* xlen  = (const int*)d_in[9];
    float* outp      = (float*)d_out;

    char* ws = (char*)d_ws;
    float* x1w  = (float*)(ws);                        // 16 MiB [8,2048,256]
    float* x2tw = (float*)(ws + 16u * 1024 * 1024);    // 16 MiB [8,256,2048] (transposed)
    float* xpw  = (float*)(ws + 32u * 1024 * 1024);    // 32 MiB [8,2048,512]
    float* yaw  = (float*)(ws + 64u * 1024 * 1024);    // 32 MiB [8,2048,512]

    hipLaunchKernelGGL(k1_proj, dim3(1024), dim3(256), 0, stream,
                       x, wg, bg, w1, b1, w2, b2, xpw, x1w, x2tw);
    hipLaunchKernelGGL(k2_attn, dim3(1024), dim3(512), 0, stream,
                       x1w, x2tw, xpw, xlen, yaw);
    hipLaunchKernelGGL(k3_out, dim3(1024), dim3(256), 0, stream,
                       yaw, wzw, wzb, x, outp);
}

// Round 4
// 966.384 us; speedup vs baseline: 1.9362x; 1.1367x over previous
//
#include <hip/hip_runtime.h>

// B=8, L=2048, D=512, H=512, E=256, K=30.  fp32 I/O, x_lengths int32.
// Identity: softmax -> key-mask -> renorm -> top-30 -> renorm ==
//   softmax over the 30 largest raw logits among valid keys (len >= 1024 >> 30).
// Score phase runs on packed f16 (v_dot2_f32_f16, fp32 accumulate).

typedef _Float16 h2 __attribute__((ext_vector_type(2)));

__device__ __forceinline__ h2 as_h2(float f) {
    union { float f; h2 h; } u; u.f = f; return u.h;
}
__device__ __forceinline__ float packh2(float a, float b) {
    union { h2 h; float f; } u; u.h.x = (_Float16)a; u.h.y = (_Float16)b; return u.f;
}

// ---------------------------------------------------------------------------
// k1: fused projection GEMM.
//   xp  [b,i,512] fp32 = x@wg+bg
//   x1p [b,i,128] h2   = (x@t1+b1) packed in e-pairs
//   x2tp[b,128,2048] h2 = (x@t2+b2)^T packed: slot ep holds (e=2ep, 2ep+1) per key
// 16 rows/block, 256 threads, thread tile = 4 rows x 16 cols.
// ---------------------------------------------------------------------------
__global__ __launch_bounds__(256) void k1_proj(
    const float* __restrict__ x,
    const float* __restrict__ wg, const float* __restrict__ bg,
    const float* __restrict__ w1, const float* __restrict__ b1,
    const float* __restrict__ w2, const float* __restrict__ b2,
    float* __restrict__ xp, float* __restrict__ x1p, float* __restrict__ x2tp)
{
    __shared__ float xs[16][512];                 // 32 KB; reused for x2 transpose
    const int t = threadIdx.x;
    const int m0 = blockIdx.x * 16;

    #pragma unroll
    for (int q = 0; q < 8; ++q) {                 // 16x512 fp32 tile -> LDS
        int f = t * 4 + 1024 * q;
        int r = f >> 9, k = f & 511;
        *(float4*)&xs[r][k] = *(const float4*)(x + (size_t)(m0 + r) * 512 + k);
    }
    __syncthreads();

    const int rg = t >> 6, ct = t & 63;
    const int r0 = rg * 4;

    float acc[4][16];
    #pragma unroll
    for (int i = 0; i < 4; ++i)
        #pragma unroll
        for (int c = 0; c < 16; ++c) acc[i][c] = 0.f;

    const float* wp[4];
    int wstr[4];
    wp[0] = wg + ct * 4;        wstr[0] = 512;    // x_prime cols [0,256)
    wp[1] = wg + 256 + ct * 4;  wstr[1] = 512;    // x_prime cols [256,512)
    wp[2] = w1 + ct * 4;        wstr[2] = 256;    // x1
    wp[3] = w2 + ct * 4;        wstr[3] = 256;    // x2

    for (int k = 0; k < 512; ++k) {
        float xv[4];
        #pragma unroll
        for (int i = 0; i < 4; ++i) xv[i] = xs[r0 + i][k];   // LDS broadcast
        #pragma unroll
        for (int p = 0; p < 4; ++p) {
            float4 u = *(const float4*)wp[p];
            wp[p] += wstr[p];
            #pragma unroll
            for (int i = 0; i < 4; ++i) {
                acc[i][p * 4 + 0] = fmaf(xv[i], u.x, acc[i][p * 4 + 0]);
                acc[i][p * 4 + 1] = fmaf(xv[i], u.y, acc[i][p * 4 + 1]);
                acc[i][p * 4 + 2] = fmaf(xv[i], u.z, acc[i][p * 4 + 2]);
                acc[i][p * 4 + 3] = fmaf(xv[i], u.w, acc[i][p * 4 + 3]);
            }
        }
    }

    float4 ub[4];
    ub[0] = *(const float4*)(bg + ct * 4);
    ub[1] = *(const float4*)(bg + 256 + ct * 4);
    ub[2] = *(const float4*)(b1 + ct * 4);
    ub[3] = *(const float4*)(b2 + ct * 4);

    // x_prime fp32 stores
    #pragma unroll
    for (int p = 0; p < 2; ++p) {
        int col = p * 256 + ct * 4;
        #pragma unroll
        for (int i = 0; i < 4; ++i) {
            float4 o;
            o.x = acc[i][p * 4 + 0] + ub[p].x;
            o.y = acc[i][p * 4 + 1] + ub[p].y;
            o.z = acc[i][p * 4 + 2] + ub[p].z;
            o.w = acc[i][p * 4 + 3] + ub[p].w;
            *(float4*)(xp + (size_t)(m0 + r0 + i) * 512 + col) = o;
        }
    }

    // x1 packed-h2 stores: thread owns e-pairs {ct*2, ct*2+1} for its 4 rows
    #pragma unroll
    for (int i = 0; i < 4; ++i) {
        float2 o;
        o.x = packh2(acc[i][8]  + ub[2].x, acc[i][9]  + ub[2].y);
        o.y = packh2(acc[i][10] + ub[2].z, acc[i][11] + ub[2].w);
        *(float2*)(x1p + (size_t)(m0 + r0 + i) * 128 + ct * 2) = o;
    }

    __syncthreads();                              // done reading xs

    // x2 -> padded LDS stash (stride 260 to break column-read conflicts)
    float* xs2 = &xs[0][0];                       // [16][260]
    #pragma unroll
    for (int i = 0; i < 4; ++i) {
        float4 o;
        o.x = acc[i][12] + ub[3].x;
        o.y = acc[i][13] + ub[3].y;
        o.z = acc[i][14] + ub[3].z;
        o.w = acc[i][15] + ub[3].w;
        *(float4*)(xs2 + (r0 + i) * 260 + ct * 4) = o;
    }
    __syncthreads();

    {   // transpose + pack: thread (key = t&15, g = t>>4) handles eps g*8..g*8+7
        const int k  = t & 15, g = t >> 4;
        const int b  = m0 >> 11;
        const int j0 = m0 & 2047;
        #pragma unroll
        for (int q = 0; q < 8; ++q) {
            int ep = g * 8 + q;
            float lo = xs2[k * 260 + 2 * ep];
            float hi = xs2[k * 260 + 2 * ep + 1];
            x2tp[((size_t)b * 128 + ep) * 2048 + j0 + k] = packh2(lo, hi);
        }
    }
}

// ---------------------------------------------------------------------------
// k2: 512 threads, 16 query rows/block.  Wave w owns rows {2w, 2w+1}.
// Scores accumulate directly in the top-k register layout
// (key j = c*256 + lane*4 + i  <->  reg q = c*4+i), fed by coalesced f16
// x2tp reads and v_dot2_f32_f16.  Then mask, top-30, softmax, gather.
// ---------------------------------------------------------------------------
__global__ __launch_bounds__(512, 4) void k2_attn(
    const float* __restrict__ x1p, const float* __restrict__ x2tp,
    const float* __restrict__ xp, const int* __restrict__ xlen,
    float* __restrict__ ya)
{
    __shared__ float x1s[16][128];                // h2-packed rows, 8 KB
    __shared__ float tkv[16][30];
    __shared__ int   tki[16][30];

    const int t  = threadIdx.x;
    const int b  = blockIdx.x >> 7;               // 128 row-blocks per batch
    const int i0 = (blockIdx.x & 127) * 16;
    const int len = xlen[b];

    {   // 16x128 h2 -> LDS, one float4 per thread
        const float* x1b = x1p + ((size_t)b * 2048 + i0) * 128;
        int f = t * 4;
        if (f < 2048) *(float4*)&x1s[0][f] = *(const float4*)(x1b + f);
    }
    __syncthreads();

    const int lane = t & 63, wid = t >> 6;        // wid 0..7
    const int r0 = wid * 2;
    const int cbase = lane * 4;

    float a0[32], a1[32];
    #pragma unroll
    for (int q = 0; q < 32; ++q) { a0[q] = 0.f; a1[q] = 0.f; }

    // ---- scores: per e-pair, 8 coalesced float4 chunks (4 keys x h2 each) ----
    const float* x2tb = x2tp + (size_t)b * 128 * 2048;
    for (int ep = 0; ep < 128; ++ep) {
        const float* row = x2tb + (size_t)ep * 2048 + cbase;
        const h2 xv0 = as_h2(x1s[r0][ep]);        // LDS broadcast
        const h2 xv1 = as_h2(x1s[r0 + 1][ep]);
        #pragma unroll
        for (int c = 0; c < 8; ++c) {
            float4 u = *(const float4*)(row + c * 256);
            a0[c*4+0] = __builtin_amdgcn_fdot2(xv0, as_h2(u.x), a0[c*4+0], false);
            a0[c*4+1] = __builtin_amdgcn_fdot2(xv0, as_h2(u.y), a0[c*4+1], false);
            a0[c*4+2] = __builtin_amdgcn_fdot2(xv0, as_h2(u.z), a0[c*4+2], false);
            a0[c*4+3] = __builtin_amdgcn_fdot2(xv0, as_h2(u.w), a0[c*4+3], false);
            a1[c*4+0] = __builtin_amdgcn_fdot2(xv1, as_h2(u.x), a1[c*4+0], false);
            a1[c*4+1] = __builtin_amdgcn_fdot2(xv1, as_h2(u.y), a1[c*4+1], false);
            a1[c*4+2] = __builtin_amdgcn_fdot2(xv1, as_h2(u.z), a1[c*4+2], false);
            a1[c*4+3] = __builtin_amdgcn_fdot2(xv1, as_h2(u.w), a1[c*4+3], false);
        }
    }

    // ---- key-length mask ----
    #pragma unroll
    for (int c = 0; c < 8; ++c)
        #pragma unroll
        for (int i = 0; i < 4; ++i) {
            int j = c * 256 + cbase + i;
            if (j >= len) { a0[c*4+i] = -3e38f; a1[c*4+i] = -3e38f; }
        }

    // ---- top-30 per row (wave-argmax, registers only) ----
#define TOPK_ROW(ARR, ROW)                                                  \
    for (int it = 0; it < 30; ++it) {                                       \
        float bv = -3.4e38f; int bq = 0;                                    \
        _Pragma("unroll")                                                   \
        for (int q = 0; q < 32; ++q) if (ARR[q] > bv) { bv = ARR[q]; bq = q; } \
        int bj = cbase + (bq >> 2) * 256 + (bq & 3);                        \
        _Pragma("unroll")                                                   \
        for (int off = 32; off > 0; off >>= 1) {                            \
            float ov = __shfl_xor(bv, off);                                 \
            int   oj = __shfl_xor(bj, off);                                 \
            if (ov > bv || (ov == bv && oj < bj)) { bv = ov; bj = oj; }     \
        }                                                                   \
        if (lane == 0) { tkv[ROW][it] = bv; tki[ROW][it] = bj; }            \
        const int jl = (bj >> 2) & 63;                                      \
        const int myq = (jl == lane) ? (((bj >> 8) << 2) | (bj & 3)) : -1;  \
        _Pragma("unroll")                                                   \
        for (int q = 0; q < 32; ++q) if (q == myq) ARR[q] = -3.4e38f;       \
    }

    TOPK_ROW(a0, r0)
    TOPK_ROW(a1, r0 + 1)
#undef TOPK_ROW
    __syncthreads();

    // ---- softmax over 30 + gather-weighted sum of x_prime rows ----
    const int g  = t >> 8;                        // 0..1 -> rows g*8..g*8+8
    const int h0 = (t & 255) * 2;
    for (int r = g * 8; r < g * 8 + 8; ++r) {
        const float v0 = tkv[r][0];               // iteration-0 argmax == max
        float wvv[30]; float s = 0.f;
        #pragma unroll
        for (int k = 0; k < 30; ++k) { wvv[k] = __expf(tkv[r][k] - v0); s += wvv[k]; }
        const float inv = 1.f / s;
        float y0 = 0.f, y1 = 0.f;
        #pragma unroll
        for (int k = 0; k < 30; ++k) {
            int j = tki[r][k];
            float2 u = *(const float2*)(xp + ((size_t)b * 2048 + j) * 512 + h0);
            y0 = fmaf(wvv[k], u.x, y0);
            y1 = fmaf(wvv[k], u.y, y1);
        }
        float2 o; o.x = y0 * inv; o.y = y1 * inv;
        *(float2*)(ya + ((size_t)b * 2048 + i0 + r) * 512 + h0) = o;
    }
}

// ---------------------------------------------------------------------------
// k3: out = x + y_att @ w_z + b_z.  16 rows/block, thread tile 4x8.
// ---------------------------------------------------------------------------
__global__ __launch_bounds__(256) void k3_out(
    const float* __restrict__ ya, const float* __restrict__ wz,
    const float* __restrict__ bz, const float* __restrict__ x,
    float* __restrict__ out)
{
    __shared__ float ys[16][512];
    const int t = threadIdx.x;
    const int m0 = blockIdx.x * 16;

    #pragma unroll
    for (int q = 0; q < 8; ++q) {
        int f = t * 4 + 1024 * q;
        int r = f >> 9, k = f & 511;
        *(float4*)&ys[r][k] = *(const float4*)(ya + (size_t)(m0 + r) * 512 + k);
    }
    __syncthreads();

    const int rg = t >> 6, ct = t & 63;
    const int r0 = rg * 4;

    float acc[4][8];
    #pragma unroll
    for (int i = 0; i < 4; ++i)
        #pragma unroll
        for (int c = 0; c < 8; ++c) acc[i][c] = 0.f;

    const float* wp0 = wz + ct * 4;
    const float* wp1 = wz + 256 + ct * 4;

    for (int k = 0; k < 512; ++k) {
        float xv[4];
        #pragma unroll
        for (int i = 0; i < 4; ++i) xv[i] = ys[r0 + i][k];
        float4 u0 = *(const float4*)wp0; wp0 += 512;
        float4 u1 = *(const float4*)wp1; wp1 += 512;
        #pragma unroll
        for (int i = 0; i < 4; ++i) {
            acc[i][0] = fmaf(xv[i], u0.x, acc[i][0]);
            acc[i][1] = fmaf(xv[i], u0.y, acc[i][1]);
            acc[i][2] = fmaf(xv[i], u0.z, acc[i][2]);
            acc[i][3] = fmaf(xv[i], u0.w, acc[i][3]);
            acc[i][4] = fmaf(xv[i], u1.x, acc[i][4]);
            acc[i][5] = fmaf(xv[i], u1.y, acc[i][5]);
            acc[i][6] = fmaf(xv[i], u1.z, acc[i][6]);
            acc[i][7] = fmaf(xv[i], u1.w, acc[i][7]);
        }
    }

    float4 ub0 = *(const float4*)(bz + ct * 4);
    float4 ub1 = *(const float4*)(bz + 256 + ct * 4);
    float bb[8] = { ub0.x, ub0.y, ub0.z, ub0.w, ub1.x, ub1.y, ub1.z, ub1.w };

    #pragma unroll
    for (int i = 0; i < 4; ++i) {
        size_t mrow = (size_t)(m0 + r0 + i);
        #pragma unroll
        for (int p = 0; p < 2; ++p) {
            int n = ct * 4 + 256 * p;
            float4 xu = *(const float4*)(x + mrow * 512 + n);
            float4 o;
            o.x = acc[i][p * 4 + 0] + bb[p * 4 + 0] + xu.x;
            o.y = acc[i][p * 4 + 1] + bb[p * 4 + 1] + xu.y;
            o.z = acc[i][p * 4 + 2] + bb[p * 4 + 2] + xu.z;
            o.w = acc[i][p * 4 + 3] + bb[p * 4 + 3] + xu.w;
            *(float4*)(out + mrow * 512 + n) = o;
        }
    }
}

extern "C" void kernel_launch(void* const* d_in, const int* in_sizes, int n_in,
                              void* d_out, int out_size, void* d_ws, size_t ws_size,
                              hipStream_t stream)
{
    (void)in_sizes; (void)n_in; (void)out_size; (void)ws_size;

    const float* x   = (const float*)d_in[0];
    const float* wg  = (const float*)d_in[1];
    const float* bg  = (const float*)d_in[2];
    const float* w1  = (const float*)d_in[3];
    const float* b1  = (const float*)d_in[4];
    const float* w2  = (const float*)d_in[5];
    const float* b2  = (const float*)d_in[6];
    const float* wzw = (const float*)d_in[7];
    const float* wzb = (const float*)d_in[8];
    const int* xlen  = (const int*)d_in[9];
    float* outp      = (float*)d_out;

    char* ws = (char*)d_ws;
    float* x1pw  = (float*)(ws);                       //  8 MiB [8,2048,128] h2
    float* x2tpw = (float*)(ws +  8u * 1024 * 1024);   //  8 MiB [8,128,2048] h2
    float* xpw   = (float*)(ws + 16u * 1024 * 1024);   // 32 MiB [8,2048,512] fp32
    float* yaw   = (float*)(ws + 48u * 1024 * 1024);   // 32 MiB [8,2048,512] fp32

    hipLaunchKernelGGL(k1_proj, dim3(1024), dim3(256), 0, stream,
                       x, wg, bg, w1, b1, w2, b2, xpw, x1pw, x2tpw);
    hipLaunchKernelGGL(k2_attn, dim3(1024), dim3(512), 0, stream,
                       x1pw, x2tpw, xpw, xlen, yaw);
    hipLaunchKernelGGL(k3_out, dim3(1024), dim3(256), 0, stream,
                       yaw, wzw, wzb, x, outp);
}

// Round 6
// 523.457 us; speedup vs baseline: 3.5745x; 1.8462x over previous
//
#include <hip/hip_runtime.h>

// B=8, L=2048, D=512, H=512, E=256, K=30.  fp32 I/O, x_lengths int32.
// Identity: softmax -> key-mask -> renorm -> top-30 -> renorm ==
//   softmax over the 30 largest raw logits among valid keys (len >= 1024 >> 30).
// GEMMs (k1,k3) on f16 MFMA (fp32 accum); scores on v_dot2_f32_f16.

typedef _Float16 h2   __attribute__((ext_vector_type(2)));
typedef _Float16 h4   __attribute__((ext_vector_type(4)));
typedef _Float16 h8   __attribute__((ext_vector_type(8)));
typedef float    f32x4 __attribute__((ext_vector_type(4)));

__device__ __forceinline__ h2 as_h2(float f) {
    union { float f; h2 h; } u; u.f = f; return u.h;
}
__device__ __forceinline__ float packh2(float a, float b) {
    union { h2 h; float f; } u; u.h.x = (_Float16)a; u.h.y = (_Float16)b; return u.f;
}

// ---------------------------------------------------------------------------
// k0: transpose-pack fp32 [K][N] -> f16 [N][K].  32x32 tiles.
// ---------------------------------------------------------------------------
__global__ __launch_bounds__(256) void k0_tp(
    const float* __restrict__ src, _Float16* __restrict__ dst, int Kd, int Nd)
{
    __shared__ float tile[32][33];
    const int t = threadIdx.x;
    const int n0 = blockIdx.x * 32, k0 = blockIdx.y * 32;
    const int r = t >> 3, c = (t & 7) * 4;
    *(float4*)&tile[r][c] = *(const float4*)(src + (size_t)(k0 + r) * Nd + n0 + c);
    __syncthreads();
    h4 hv;
    hv.x = (_Float16)tile[c + 0][r];
    hv.y = (_Float16)tile[c + 1][r];
    hv.z = (_Float16)tile[c + 2][r];
    hv.w = (_Float16)tile[c + 3][r];
    *(h4*)(dst + (size_t)(n0 + r) * Kd + k0 + c) = hv;
}

// ---------------------------------------------------------------------------
// k1: MFMA projection GEMM.  BM=64 rows x BN=256 cols, BK=64, 4 waves.
// blockIdx.y = col-block: 0,1 -> x_prime (h2-packed xph), 2 -> x1 (x1p),
// 3 -> x2 (transposed packed x2tp via LDS tile).
// ---------------------------------------------------------------------------
__global__ __launch_bounds__(256) void k1_mfma(
    const float* __restrict__ x, const _Float16* __restrict__ wT,
    const float* __restrict__ bg, const float* __restrict__ b1,
    const float* __restrict__ b2,
    float* __restrict__ xph, float* __restrict__ x1p, float* __restrict__ x2tp)
{
    __shared__ __align__(16) char lds_raw[40960];
    _Float16* Alds = (_Float16*)lds_raw;             // [64][64] f16 = 8 KB
    _Float16* Blds = (_Float16*)(lds_raw + 8192);    // [256][64] f16 = 32 KB

    const int t = threadIdx.x;
    const int m0 = blockIdx.x * 64;
    const int cb = blockIdx.y;
    const int n0 = cb * 256;                         // row base in wT
    const int lane = t & 63, w = t >> 6;
    const int arow = lane & 15, ak = (lane >> 4) * 8;

    f32x4 acc[4][4];
    #pragma unroll
    for (int i = 0; i < 4; ++i)
        #pragma unroll
        for (int j = 0; j < 4; ++j) acc[i][j] = (f32x4){0.f, 0.f, 0.f, 0.f};

    for (int k0 = 0; k0 < 512; k0 += 64) {
        __syncthreads();
        {   // stage A: 64 rows x 64 k fp32 -> f16
            const int r = t >> 2, c0 = (t & 3) * 16;
            const float* src = x + (size_t)(m0 + r) * 512 + k0 + c0;
            #pragma unroll
            for (int hvi = 0; hvi < 2; ++hvi) {
                float4 u0 = *(const float4*)(src + hvi * 8);
                float4 u1 = *(const float4*)(src + hvi * 8 + 4);
                h8 hv;
                hv[0] = (_Float16)u0.x; hv[1] = (_Float16)u0.y;
                hv[2] = (_Float16)u0.z; hv[3] = (_Float16)u0.w;
                hv[4] = (_Float16)u1.x; hv[5] = (_Float16)u1.y;
                hv[6] = (_Float16)u1.z; hv[7] = (_Float16)u1.w;
                *(h8*)(Alds + r * 64 + c0 + hvi * 8) = hv;
            }
        }
        {   // stage B: 256 n-rows x 64 k f16.  8 lanes cover one 128B row.
            #pragma unroll
            for (int i = 0; i < 8; ++i) {
                int idx = t + i * 256;               // 0..2047
                int row = idx >> 3, ch = idx & 7;
                *(float4*)(Blds + row * 64 + ch * 8) =
                    *(const float4*)(wT + (size_t)(n0 + row) * 512 + k0 + ch * 8);
            }
        }
        __syncthreads();

        #pragma unroll
        for (int kk = 0; kk < 2; ++kk) {
            h8 af[4], bf[4];
            #pragma unroll
            for (int rb = 0; rb < 4; ++rb)
                af[rb] = *(const h8*)(Alds + (rb * 16 + arow) * 64 + kk * 32 + ak);
            #pragma unroll
            for (int cf = 0; cf < 4; ++cf)
                bf[cf] = *(const h8*)(Blds + (w * 64 + cf * 16 + arow) * 64 + kk * 32 + ak);
            #pragma unroll
            for (int rb = 0; rb < 4; ++rb)
                #pragma unroll
                for (int cf = 0; cf < 4; ++cf)
                    acc[rb][cf] = __builtin_amdgcn_mfma_f32_16x16x32_f16(
                        af[rb], bf[cf], acc[rb][cf], 0, 0, 0);
        }
    }

    const float* bias = (cb < 2) ? (bg + cb * 256) : (cb == 2 ? b1 : b2);

    if (cb < 3) {
        // pack e-pairs via lane shuffle; even lanes store 4B
        float* dst; int epbase; size_t rstr;
        if (cb < 2) { dst = xph; epbase = cb * 128; rstr = 256; }
        else        { dst = x1p; epbase = 0;        rstr = 128; }
        #pragma unroll
        for (int cf = 0; cf < 4; ++cf) {
            const int c = w * 64 + cf * 16 + arow;
            const float bv = bias[c];
            #pragma unroll
            for (int rb = 0; rb < 4; ++rb) {
                #pragma unroll
                for (int j = 0; j < 4; ++j) {
                    float v = acc[rb][cf][j] + bv;
                    float o = __shfl_xor(v, 1);
                    if ((lane & 1) == 0) {
                        int row = m0 + rb * 16 + (lane >> 4) * 4 + j;
                        dst[(size_t)row * rstr + epbase + (c >> 1)] = packh2(v, o);
                    }
                }
            }
        }
    } else {
        // x2: pack pairs -> LDS tile T[ep][key] (stride 68) -> coalesced store
        __syncthreads();                              // done with Alds/Blds
        float* T = (float*)lds_raw;                   // [128][68] floats = 34816 B
        #pragma unroll
        for (int cf = 0; cf < 4; ++cf) {
            const int c = w * 64 + cf * 16 + arow;
            const float bv = bias[c];
            #pragma unroll
            for (int rb = 0; rb < 4; ++rb) {
                #pragma unroll
                for (int j = 0; j < 4; ++j) {
                    float v = acc[rb][cf][j] + bv;
                    float o = __shfl_xor(v, 1);
                    if ((lane & 1) == 0)
                        T[(c >> 1) * 68 + rb * 16 + (lane >> 4) * 4 + j] = packh2(v, o);
                }
            }
        }
        __syncthreads();
        const int bb = m0 >> 11, j0 = m0 & 2047;
        #pragma unroll
        for (int g = 0; g < 8; ++g) {
            int idx4 = t + g * 256;                   // 0..2047
            int ep = idx4 >> 4, ko = (idx4 & 15) * 4;
            float4 vv = *(const float4*)(T + ep * 68 + ko);
            *(float4*)(x2tp + ((size_t)bb * 128 + ep) * 2048 + j0 + ko) = vv;
        }
    }
}

// ---------------------------------------------------------------------------
// k2: 512 threads, 16 query rows/block.  Wave w owns rows {2w, 2w+1}.
// Scores in top-k register layout (key j = c*256 + lane*4 + i), coalesced f16
// x2tp reads + v_dot2_f32_f16.  Mask, top-30, softmax, h2-packed gather.
// ---------------------------------------------------------------------------
__global__ __launch_bounds__(512, 4) void k2_attn(
    const float* __restrict__ x1p, const float* __restrict__ x2tp,
    const float* __restrict__ xph, const int* __restrict__ xlen,
    float* __restrict__ yah)
{
    __shared__ float x1s[16][128];                // h2-packed rows, 8 KB
    __shared__ float tkv[16][30];
    __shared__ int   tki[16][30];

    const int t  = threadIdx.x;
    const int b  = blockIdx.x >> 7;               // 128 row-blocks per batch
    const int i0 = (blockIdx.x & 127) * 16;
    const int len = xlen[b];

    {   // 16x128 h2 -> LDS
        const float* x1b = x1p + ((size_t)b * 2048 + i0) * 128;
        int f = t * 4;
        if (f < 2048) *(float4*)&x1s[0][f] = *(const float4*)(x1b + f);
    }
    __syncthreads();

    const int lane = t & 63, wid = t >> 6;
    const int r0 = wid * 2;
    const int cbase = lane * 4;

    float a0[32], a1[32];
    #pragma unroll
    for (int q = 0; q < 32; ++q) { a0[q] = 0.f; a1[q] = 0.f; }

    const float* x2tb = x2tp + (size_t)b * 128 * 2048;
    for (int ep = 0; ep < 128; ++ep) {
        const float* row = x2tb + (size_t)ep * 2048 + cbase;
        const h2 xv0 = as_h2(x1s[r0][ep]);
        const h2 xv1 = as_h2(x1s[r0 + 1][ep]);
        #pragma unroll
        for (int c = 0; c < 8; ++c) {
            float4 u = *(const float4*)(row + c * 256);
            a0[c*4+0] = __builtin_amdgcn_fdot2(xv0, as_h2(u.x), a0[c*4+0], false);
            a0[c*4+1] = __builtin_amdgcn_fdot2(xv0, as_h2(u.y), a0[c*4+1], false);
            a0[c*4+2] = __builtin_amdgcn_fdot2(xv0, as_h2(u.z), a0[c*4+2], false);
            a0[c*4+3] = __builtin_amdgcn_fdot2(xv0, as_h2(u.w), a0[c*4+3], false);
            a1[c*4+0] = __builtin_amdgcn_fdot2(xv1, as_h2(u.x), a1[c*4+0], false);
            a1[c*4+1] = __builtin_amdgcn_fdot2(xv1, as_h2(u.y), a1[c*4+1], false);
            a1[c*4+2] = __builtin_amdgcn_fdot2(xv1, as_h2(u.z), a1[c*4+2], false);
            a1[c*4+3] = __builtin_amdgcn_fdot2(xv1, as_h2(u.w), a1[c*4+3], false);
        }
    }

    #pragma unroll
    for (int c = 0; c < 8; ++c)
        #pragma unroll
        for (int i = 0; i < 4; ++i) {
            int j = c * 256 + cbase + i;
            if (j >= len) { a0[c*4+i] = -3e38f; a1[c*4+i] = -3e38f; }
        }

#define TOPK_ROW(ARR, ROW)                                                  \
    for (int it = 0; it < 30; ++it) {                                       \
        float bv = -3.4e38f; int bq = 0;                                    \
        _Pragma("unroll")                                                   \
        for (int q = 0; q < 32; ++q) if (ARR[q] > bv) { bv = ARR[q]; bq = q; } \
        int bj = cbase + (bq >> 2) * 256 + (bq & 3);                        \
        _Pragma("unroll")                                                   \
        for (int off = 32; off > 0; off >>= 1) {                            \
            float ov = __shfl_xor(bv, off);                                 \
            int   oj = __shfl_xor(bj, off);                                 \
            if (ov > bv || (ov == bv && oj < bj)) { bv = ov; bj = oj; }     \
        }                                                                   \
        if (lane == 0) { tkv[ROW][it] = bv; tki[ROW][it] = bj; }            \
        const int jl = (bj >> 2) & 63;                                      \
        const int myq = (jl == lane) ? (((bj >> 8) << 2) | (bj & 3)) : -1;  \
        _Pragma("unroll")                                                   \
        for (int q = 0; q < 32; ++q) if (q == myq) ARR[q] = -3.4e38f;       \
    }

    TOPK_ROW(a0, r0)
    TOPK_ROW(a1, r0 + 1)
#undef TOPK_ROW
    __syncthreads();

    // softmax over 30 + gather of h2-packed x_prime
    const int g  = t >> 8;                        // 0..1 -> rows g*8..g*8+8
    const int hp = t & 255;                       // h2-pair index
    for (int r = g * 8; r < g * 8 + 8; ++r) {
        const float v0 = tkv[r][0];
        float wvv[30]; float s = 0.f;
        #pragma unroll
        for (int k = 0; k < 30; ++k) { wvv[k] = __expf(tkv[r][k] - v0); s += wvv[k]; }
        const float inv = 1.f / s;
        float y0 = 0.f, y1 = 0.f;
        #pragma unroll
        for (int k = 0; k < 30; ++k) {
            int j = tki[r][k];
            h2 u = as_h2(xph[((size_t)b * 2048 + j) * 256 + hp]);
            y0 = fmaf(wvv[k], (float)u.x, y0);
            y1 = fmaf(wvv[k], (float)u.y, y1);
        }
        yah[((size_t)b * 2048 + i0 + r) * 256 + hp] = packh2(y0 * inv, y1 * inv);
    }
}

// ---------------------------------------------------------------------------
// k3: out = x + yah @ wzT^T + bz.  MFMA, BM=64, BN=256 (2 col-blocks), BK=64.
// ---------------------------------------------------------------------------
__global__ __launch_bounds__(256) void k3_mfma(
    const float* __restrict__ yah, const _Float16* __restrict__ wzT,
    const float* __restrict__ bz, const float* __restrict__ x,
    float* __restrict__ out)
{
    __shared__ __align__(16) char lds_raw[40960];
    _Float16* Alds = (_Float16*)lds_raw;             // [64][64]
    _Float16* Blds = (_Float16*)(lds_raw + 8192);    // [256][64]

    const int t = threadIdx.x;
    const int m0 = blockIdx.x * 64;
    const int n0 = blockIdx.y * 256;
    const int lane = t & 63, w = t >> 6;
    const int arow = lane & 15, ak = (lane >> 4) * 8;

    f32x4 acc[4][4];
    #pragma unroll
    for (int i = 0; i < 4; ++i)
        #pragma unroll
        for (int j = 0; j < 4; ++j) acc[i][j] = (f32x4){0.f, 0.f, 0.f, 0.f};

    for (int k0 = 0; k0 < 512; k0 += 64) {
        __syncthreads();
        {   // stage A: h2-packed rows, pure copy. 64 rows x 32 floats
            const int r = t >> 2, c0 = (t & 3) * 8;   // float chunk
            const float4* src = (const float4*)(yah + (size_t)(m0 + r) * 256 + k0 / 2 + c0);
            float4* dst = (float4*)(Alds + r * 64 + c0 * 2);
            dst[0] = src[0]; dst[1] = src[1];
        }
        {   // stage B: 256 n-rows x 64 k f16.  8 lanes cover one 128B row.
            #pragma unroll
            for (int i = 0; i < 8; ++i) {
                int idx = t + i * 256;               // 0..2047
                int row = idx >> 3, ch = idx & 7;
                *(float4*)(Blds + row * 64 + ch * 8) =
                    *(const float4*)(wzT + (size_t)(n0 + row) * 512 + k0 + ch * 8);
            }
        }
        __syncthreads();

        #pragma unroll
        for (int kk = 0; kk < 2; ++kk) {
            h8 af[4], bf[4];
            #pragma unroll
            for (int rb = 0; rb < 4; ++rb)
                af[rb] = *(const h8*)(Alds + (rb * 16 + arow) * 64 + kk * 32 + ak);
            #pragma unroll
            for (int cf = 0; cf < 4; ++cf)
                bf[cf] = *(const h8*)(Blds + (w * 64 + cf * 16 + arow) * 64 + kk * 32 + ak);
            #pragma unroll
            for (int rb = 0; rb < 4; ++rb)
                #pragma unroll
                for (int cf = 0; cf < 4; ++cf)
                    acc[rb][cf] = __builtin_amdgcn_mfma_f32_16x16x32_f16(
                        af[rb], bf[cf], acc[rb][cf], 0, 0, 0);
        }
    }

    #pragma unroll
    for (int cf = 0; cf < 4; ++cf) {
        const int c = n0 + w * 64 + cf * 16 + arow;
        const float bv = bz[c];
        #pragma unroll
        for (int rb = 0; rb < 4; ++rb) {
            #pragma unroll
            for (int j = 0; j < 4; ++j) {
                int row = m0 + rb * 16 + (lane >> 4) * 4 + j;
                out[(size_t)row * 512 + c] =
                    acc[rb][cf][j] + bv + x[(size_t)row * 512 + c];
            }
        }
    }
}

extern "C" void kernel_launch(void* const* d_in, const int* in_sizes, int n_in,
                              void* d_out, int out_size, void* d_ws, size_t ws_size,
                              hipStream_t stream)
{
    (void)in_sizes; (void)n_in; (void)out_size; (void)ws_size;

    const float* x   = (const float*)d_in[0];
    const float* wg  = (const float*)d_in[1];
    const float* bg  = (const float*)d_in[2];
    const float* w1  = (const float*)d_in[3];
    const float* b1  = (const float*)d_in[4];
    const float* w2  = (const float*)d_in[5];
    const float* b2  = (const float*)d_in[6];
    const float* wzw = (const float*)d_in[7];
    const float* wzb = (const float*)d_in[8];
    const int* xlen  = (const int*)d_in[9];
    float* outp      = (float*)d_out;

    char* ws = (char*)d_ws;
    _Float16* wT   = (_Float16*)(ws);                       // 1 MiB [1024][512] f16
    _Float16* wzT  = (_Float16*)(ws + 1u * 1024 * 1024);    // 0.5 MiB [512][512] f16
    float* x1pw    = (float*)(ws +  2u * 1024 * 1024);      // 8 MiB [16384][128] h2
    float* x2tpw   = (float*)(ws + 10u * 1024 * 1024);      // 8 MiB [8][128][2048] h2
    float* xphw    = (float*)(ws + 18u * 1024 * 1024);      // 16 MiB [16384][256] h2
    float* yahw    = (float*)(ws + 34u * 1024 * 1024);      // 16 MiB [16384][256] h2

    // k0: pack weights (transposed, f16)
    hipLaunchKernelGGL(k0_tp, dim3(16, 16), dim3(256), 0, stream, wg,  wT,            512, 512);
    hipLaunchKernelGGL(k0_tp, dim3(8, 16),  dim3(256), 0, stream, w1,  wT + 512*512,  512, 256);
    hipLaunchKernelGGL(k0_tp, dim3(8, 16),  dim3(256), 0, stream, w2,  wT + 768*512,  512, 256);
    hipLaunchKernelGGL(k0_tp, dim3(16, 16), dim3(256), 0, stream, wzw, wzT,           512, 512);

    hipLaunchKernelGGL(k1_mfma, dim3(256, 4), dim3(256), 0, stream,
                       x, wT, bg, b1, b2, xphw, x1pw, x2tpw);
    hipLaunchKernelGGL(k2_attn, dim3(1024), dim3(512), 0, stream,
                       x1pw, x2tpw, xphw, xlen, yahw);
    hipLaunchKernelGGL(k3_mfma, dim3(256, 2), dim3(256), 0, stream,
                       yahw, wzT, wzb, x, outp);
}

// Round 7
// 406.338 us; speedup vs baseline: 4.6048x; 1.2882x over previous
//
#include <hip/hip_runtime.h>

// B=8, L=2048, D=512, H=512, E=256, K=30.  fp32 I/O, x_lengths int32.
// Identity: softmax -> key-mask -> renorm -> top-30 -> renorm ==
//   softmax over the 30 largest raw logits among valid keys (len >= 1024 >> 30).
// GEMMs (k1,k3) on f16 MFMA (fp32 accum); scores on v_dot2_f32_f16.
// Top-k: index packed into low 11 bits of order-preserving uint score
// (value-only max scans, unique winners, jax tie-break = lowest index).

typedef _Float16 h2   __attribute__((ext_vector_type(2)));
typedef _Float16 h4   __attribute__((ext_vector_type(4)));
typedef _Float16 h8   __attribute__((ext_vector_type(8)));
typedef float    f32x4 __attribute__((ext_vector_type(4)));

__device__ __forceinline__ h2 as_h2(float f) {
    union { float f; h2 h; } u; u.f = f; return u.h;
}
__device__ __forceinline__ float packh2(float a, float b) {
    union { h2 h; float f; } u; u.h.x = (_Float16)a; u.h.y = (_Float16)b; return u.f;
}

// ---------------------------------------------------------------------------
// k0: transpose-pack fp32 [K][N] -> f16 [N][K].  32x32 tiles.
// ---------------------------------------------------------------------------
__global__ __launch_bounds__(256) void k0_tp(
    const float* __restrict__ src, _Float16* __restrict__ dst, int Kd, int Nd)
{
    __shared__ float tile[32][33];
    const int t = threadIdx.x;
    const int n0 = blockIdx.x * 32, k0 = blockIdx.y * 32;
    const int r = t >> 3, c = (t & 7) * 4;
    *(float4*)&tile[r][c] = *(const float4*)(src + (size_t)(k0 + r) * Nd + n0 + c);
    __syncthreads();
    h4 hv;
    hv.x = (_Float16)tile[c + 0][r];
    hv.y = (_Float16)tile[c + 1][r];
    hv.z = (_Float16)tile[c + 2][r];
    hv.w = (_Float16)tile[c + 3][r];
    *(h4*)(dst + (size_t)(n0 + r) * Kd + k0 + c) = hv;
}

// ---------------------------------------------------------------------------
// k1: MFMA projection GEMM.  BM=64 rows x BN=256 cols, BK=64, 4 waves.
// blockIdx.y = col-block: 0,1 -> x_prime (h2-packed xph), 2 -> x1 (x1p),
// 3 -> x2 (transposed packed x2tp via LDS tile).
// ---------------------------------------------------------------------------
__global__ __launch_bounds__(256) void k1_mfma(
    const float* __restrict__ x, const _Float16* __restrict__ wT,
    const float* __restrict__ bg, const float* __restrict__ b1,
    const float* __restrict__ b2,
    float* __restrict__ xph, float* __restrict__ x1p, float* __restrict__ x2tp)
{
    __shared__ __align__(16) char lds_raw[40960];
    _Float16* Alds = (_Float16*)lds_raw;             // [64][64] f16 = 8 KB
    _Float16* Blds = (_Float16*)(lds_raw + 8192);    // [256][64] f16 = 32 KB

    const int t = threadIdx.x;
    const int m0 = blockIdx.x * 64;
    const int cb = blockIdx.y;
    const int n0 = cb * 256;                         // row base in wT
    const int lane = t & 63, w = t >> 6;
    const int arow = lane & 15, ak = (lane >> 4) * 8;

    f32x4 acc[4][4];
    #pragma unroll
    for (int i = 0; i < 4; ++i)
        #pragma unroll
        for (int j = 0; j < 4; ++j) acc[i][j] = (f32x4){0.f, 0.f, 0.f, 0.f};

    for (int k0 = 0; k0 < 512; k0 += 64) {
        __syncthreads();
        {   // stage A: 64 rows x 64 k fp32 -> f16
            const int r = t >> 2, c0 = (t & 3) * 16;
            const float* src = x + (size_t)(m0 + r) * 512 + k0 + c0;
            #pragma unroll
            for (int hvi = 0; hvi < 2; ++hvi) {
                float4 u0 = *(const float4*)(src + hvi * 8);
                float4 u1 = *(const float4*)(src + hvi * 8 + 4);
                h8 hv;
                hv[0] = (_Float16)u0.x; hv[1] = (_Float16)u0.y;
                hv[2] = (_Float16)u0.z; hv[3] = (_Float16)u0.w;
                hv[4] = (_Float16)u1.x; hv[5] = (_Float16)u1.y;
                hv[6] = (_Float16)u1.z; hv[7] = (_Float16)u1.w;
                *(h8*)(Alds + r * 64 + c0 + hvi * 8) = hv;
            }
        }
        {   // stage B: 256 n-rows x 64 k f16.  8 lanes cover one 128B row.
            #pragma unroll
            for (int i = 0; i < 8; ++i) {
                int idx = t + i * 256;               // 0..2047
                int row = idx >> 3, ch = idx & 7;
                *(float4*)(Blds + row * 64 + ch * 8) =
                    *(const float4*)(wT + (size_t)(n0 + row) * 512 + k0 + ch * 8);
            }
        }
        __syncthreads();

        #pragma unroll
        for (int kk = 0; kk < 2; ++kk) {
            h8 af[4], bf[4];
            #pragma unroll
            for (int rb = 0; rb < 4; ++rb)
                af[rb] = *(const h8*)(Alds + (rb * 16 + arow) * 64 + kk * 32 + ak);
            #pragma unroll
            for (int cf = 0; cf < 4; ++cf)
                bf[cf] = *(const h8*)(Blds + (w * 64 + cf * 16 + arow) * 64 + kk * 32 + ak);
            #pragma unroll
            for (int rb = 0; rb < 4; ++rb)
                #pragma unroll
                for (int cf = 0; cf < 4; ++cf)
                    acc[rb][cf] = __builtin_amdgcn_mfma_f32_16x16x32_f16(
                        af[rb], bf[cf], acc[rb][cf], 0, 0, 0);
        }
    }

    const float* bias = (cb < 2) ? (bg + cb * 256) : (cb == 2 ? b1 : b2);

    if (cb < 3) {
        // pack e-pairs via lane shuffle; even lanes store 4B
        float* dst; int epbase; size_t rstr;
        if (cb < 2) { dst = xph; epbase = cb * 128; rstr = 256; }
        else        { dst = x1p; epbase = 0;        rstr = 128; }
        #pragma unroll
        for (int cf = 0; cf < 4; ++cf) {
            const int c = w * 64 + cf * 16 + arow;
            const float bv = bias[c];
            #pragma unroll
            for (int rb = 0; rb < 4; ++rb) {
                #pragma unroll
                for (int j = 0; j < 4; ++j) {
                    float v = acc[rb][cf][j] + bv;
                    float o = __shfl_xor(v, 1);
                    if ((lane & 1) == 0) {
                        int row = m0 + rb * 16 + (lane >> 4) * 4 + j;
                        dst[(size_t)row * rstr + epbase + (c >> 1)] = packh2(v, o);
                    }
                }
            }
        }
    } else {
        // x2: pack pairs -> LDS tile T[ep][key] (stride 68) -> coalesced store
        __syncthreads();                              // done with Alds/Blds
        float* T = (float*)lds_raw;                   // [128][68] floats = 34816 B
        #pragma unroll
        for (int cf = 0; cf < 4; ++cf) {
            const int c = w * 64 + cf * 16 + arow;
            const float bv = bias[c];
            #pragma unroll
            for (int rb = 0; rb < 4; ++rb) {
                #pragma unroll
                for (int j = 0; j < 4; ++j) {
                    float v = acc[rb][cf][j] + bv;
                    float o = __shfl_xor(v, 1);
                    if ((lane & 1) == 0)
                        T[(c >> 1) * 68 + rb * 16 + (lane >> 4) * 4 + j] = packh2(v, o);
                }
            }
        }
        __syncthreads();
        const int bb = m0 >> 11, j0 = m0 & 2047;
        #pragma unroll
        for (int g = 0; g < 8; ++g) {
            int idx4 = t + g * 256;                   // 0..2047
            int ep = idx4 >> 4, ko = (idx4 & 15) * 4;
            float4 vv = *(const float4*)(T + ep * 68 + ko);
            *(float4*)(x2tp + ((size_t)bb * 128 + ep) * 2048 + j0 + ko) = vv;
        }
    }
}

// ---------------------------------------------------------------------------
// k2: 512 threads, 16 query rows/block.  Wave w owns rows {2w, 2w+1}.
// Scores in top-k register layout (key j = c*256 + lane*4 + i), coalesced f16
// x2tp reads + v_dot2_f32_f16.  Then: order-preserving uint pack with index
// in low 11 bits, 30x value-only wave-max extraction, shared softmax weights,
// h2-packed gather.
// ---------------------------------------------------------------------------
__global__ __launch_bounds__(512, 2) void k2_attn(
    const float* __restrict__ x1p, const float* __restrict__ x2tp,
    const float* __restrict__ xph, const int* __restrict__ xlen,
    float* __restrict__ yah)
{
    __shared__ float    x1s[16][128];             // h2-packed rows, 8 KB
    __shared__ unsigned tkp[16][30];              // packed winners
    __shared__ float    wvs[16][30];              // softmax weights
    __shared__ int      tki[16][30];              // unpacked indices
    __shared__ float    vin[16];                  // 1/sum per row

    const int t  = threadIdx.x;
    const int b  = blockIdx.x >> 7;               // 128 row-blocks per batch
    const int i0 = (blockIdx.x & 127) * 16;
    const int len = xlen[b];

    {   // 16x128 h2 -> LDS
        const float* x1b = x1p + ((size_t)b * 2048 + i0) * 128;
        int f = t * 4;
        if (f < 2048) *(float4*)&x1s[0][f] = *(const float4*)(x1b + f);
    }
    __syncthreads();

    const int lane = t & 63, wid = t >> 6;
    const int r0 = wid * 2;
    const int cbase = lane * 4;

    float a0[32], a1[32];
    #pragma unroll
    for (int q = 0; q < 32; ++q) { a0[q] = 0.f; a1[q] = 0.f; }

    const float* x2tb = x2tp + (size_t)b * 128 * 2048;
    for (int ep = 0; ep < 128; ++ep) {
        const float* row = x2tb + (size_t)ep * 2048 + cbase;
        const h2 xv0 = as_h2(x1s[r0][ep]);
        const h2 xv1 = as_h2(x1s[r0 + 1][ep]);
        #pragma unroll
        for (int c = 0; c < 8; ++c) {
            float4 u = *(const float4*)(row + c * 256);
            a0[c*4+0] = __builtin_amdgcn_fdot2(xv0, as_h2(u.x), a0[c*4+0], false);
            a0[c*4+1] = __builtin_amdgcn_fdot2(xv0, as_h2(u.y), a0[c*4+1], false);
            a0[c*4+2] = __builtin_amdgcn_fdot2(xv0, as_h2(u.z), a0[c*4+2], false);
            a0[c*4+3] = __builtin_amdgcn_fdot2(xv0, as_h2(u.w), a0[c*4+3], false);
            a1[c*4+0] = __builtin_amdgcn_fdot2(xv1, as_h2(u.x), a1[c*4+0], false);
            a1[c*4+1] = __builtin_amdgcn_fdot2(xv1, as_h2(u.y), a1[c*4+1], false);
            a1[c*4+2] = __builtin_amdgcn_fdot2(xv1, as_h2(u.z), a1[c*4+2], false);
            a1[c*4+3] = __builtin_amdgcn_fdot2(xv1, as_h2(u.w), a1[c*4+3], false);
        }
    }

    // ---- pack: order-preserving uint, low 11 bits = (2047 - j) ----
    unsigned u0[32], u1[32];
    #pragma unroll
    for (int c = 0; c < 8; ++c)
        #pragma unroll
        for (int i = 0; i < 4; ++i) {
            const int j = c * 256 + cbase + i;
            const unsigned tag = (unsigned)(2047 - j);
            unsigned b0 = __float_as_uint(a0[c*4+i]);
            unsigned b1v = __float_as_uint(a1[c*4+i]);
            b0  = b0  ^ (0x80000000u | (unsigned)((int)b0  >> 31));
            b1v = b1v ^ (0x80000000u | (unsigned)((int)b1v >> 31));
            u0[c*4+i] = (j < len) ? ((b0  & 0xFFFFF800u) | tag) : 0u;
            u1[c*4+i] = (j < len) ? ((b1v & 0xFFFFF800u) | tag) : 0u;
        }

    // ---- top-30 per row: value-only wave-max extraction ----
#define TOPK_ROW(U, ROW)                                                    \
    for (int it = 0; it < 30; ++it) {                                       \
        unsigned mx = 0u;                                                   \
        _Pragma("unroll")                                                   \
        for (int q = 0; q < 32; ++q) mx = mx > U[q] ? mx : U[q];            \
        _Pragma("unroll")                                                   \
        for (int off = 32; off > 0; off >>= 1) {                            \
            unsigned o = (unsigned)__shfl_xor((int)mx, off);                \
            mx = mx > o ? mx : o;                                           \
        }                                                                   \
        if (lane == 0) tkp[ROW][it] = mx;                                   \
        _Pragma("unroll")                                                   \
        for (int q = 0; q < 32; ++q) U[q] = (U[q] == mx) ? 0u : U[q];       \
    }

    TOPK_ROW(u0, r0)
    TOPK_ROW(u1, r0 + 1)
#undef TOPK_ROW
    __syncthreads();

    // ---- unpack + per-row softmax weights (once per block) ----
    {
        const int r = t >> 5, k = t & 31;
        if (k < 30) {
            unsigned u = tkp[r][k];
            unsigned m0 = tkp[r][0] & 0xFFFFF800u;
            unsigned ub = u & 0xFFFFF800u;
            unsigned bb0 = (m0 & 0x80000000u) ? (m0 ^ 0x80000000u) : ~m0;
            unsigned bbk = (ub & 0x80000000u) ? (ub ^ 0x80000000u) : ~ub;
            float s0 = __uint_as_float(bb0);
            float sk = __uint_as_float(bbk);
            wvs[r][k] = __expf(sk - s0);
            tki[r][k] = 2047 - (int)(u & 0x7FFu);
        }
    }
    __syncthreads();
    if (t < 16) {
        float s = 0.f;
        #pragma unroll
        for (int k = 0; k < 30; ++k) s += wvs[t][k];
        vin[t] = 1.f / s;
    }
    __syncthreads();

    // ---- gather of h2-packed x_prime with shared weights ----
    const int g  = t >> 8;                        // 0..1 -> rows g*8..g*8+8
    const int hp = t & 255;                       // h2-pair index
    for (int r = g * 8; r < g * 8 + 8; ++r) {
        float y0 = 0.f, y1 = 0.f;
        #pragma unroll
        for (int k = 0; k < 30; ++k) {
            int j = tki[r][k];
            float wv = wvs[r][k];
            h2 u = as_h2(xph[((size_t)b * 2048 + j) * 256 + hp]);
            y0 = fmaf(wv, (float)u.x, y0);
            y1 = fmaf(wv, (float)u.y, y1);
        }
        const float inv = vin[r];
        yah[((size_t)b * 2048 + i0 + r) * 256 + hp] = packh2(y0 * inv, y1 * inv);
    }
}

// ---------------------------------------------------------------------------
// k3: out = x + yah @ wzT^T + bz.  MFMA, BM=64, BN=256 (2 col-blocks), BK=64.
// ---------------------------------------------------------------------------
__global__ __launch_bounds__(256) void k3_mfma(
    const float* __restrict__ yah, const _Float16* __restrict__ wzT,
    const float* __restrict__ bz, const float* __restrict__ x,
    float* __restrict__ out)
{
    __shared__ __align__(16) char lds_raw[40960];
    _Float16* Alds = (_Float16*)lds_raw;             // [64][64]
    _Float16* Blds = (_Float16*)(lds_raw + 8192);    // [256][64]

    const int t = threadIdx.x;
    const int m0 = blockIdx.x * 64;
    const int n0 = blockIdx.y * 256;
    const int lane = t & 63, w = t >> 6;
    const int arow = lane & 15, ak = (lane >> 4) * 8;

    f32x4 acc[4][4];
    #pragma unroll
    for (int i = 0; i < 4; ++i)
        #pragma unroll
        for (int j = 0; j < 4; ++j) acc[i][j] = (f32x4){0.f, 0.f, 0.f, 0.f};

    for (int k0 = 0; k0 < 512; k0 += 64) {
        __syncthreads();
        {   // stage A: h2-packed rows, pure copy. 64 rows x 32 floats
            const int r = t >> 2, c0 = (t & 3) * 8;   // float chunk
            const float4* src = (const float4*)(yah + (size_t)(m0 + r) * 256 + k0 / 2 + c0);
            float4* dst = (float4*)(Alds + r * 64 + c0 * 2);
            dst[0] = src[0]; dst[1] = src[1];
        }
        {   // stage B: 256 n-rows x 64 k f16.  8 lanes cover one 128B row.
            #pragma unroll
            for (int i = 0; i < 8; ++i) {
                int idx = t + i * 256;               // 0..2047
                int row = idx >> 3, ch = idx & 7;
                *(float4*)(Blds + row * 64 + ch * 8) =
                    *(const float4*)(wzT + (size_t)(n0 + row) * 512 + k0 + ch * 8);
            }
        }
        __syncthreads();

        #pragma unroll
        for (int kk = 0; kk < 2; ++kk) {
            h8 af[4], bf[4];
            #pragma unroll
            for (int rb = 0; rb < 4; ++rb)
                af[rb] = *(const h8*)(Alds + (rb * 16 + arow) * 64 + kk * 32 + ak);
            #pragma unroll
            for (int cf = 0; cf < 4; ++cf)
                bf[cf] = *(const h8*)(Blds + (w * 64 + cf * 16 + arow) * 64 + kk * 32 + ak);
            #pragma unroll
            for (int rb = 0; rb < 4; ++rb)
                #pragma unroll
                for (int cf = 0; cf < 4; ++cf)
                    acc[rb][cf] = __builtin_amdgcn_mfma_f32_16x16x32_f16(
                        af[rb], bf[cf], acc[rb][cf], 0, 0, 0);
        }
    }

    #pragma unroll
    for (int cf = 0; cf < 4; ++cf) {
        const int c = n0 + w * 64 + cf * 16 + arow;
        const float bv = bz[c];
        #pragma unroll
        for (int rb = 0; rb < 4; ++rb) {
            #pragma unroll
            for (int j = 0; j < 4; ++j) {
                int row = m0 + rb * 16 + (lane >> 4) * 4 + j;
                out[(size_t)row * 512 + c] =
                    acc[rb][cf][j] + bv + x[(size_t)row * 512 + c];
            }
        }
    }
}

extern "C" void kernel_launch(void* const* d_in, const int* in_sizes, int n_in,
                              void* d_out, int out_size, void* d_ws, size_t ws_size,
                              hipStream_t stream)
{
    (void)in_sizes; (void)n_in; (void)out_size; (void)ws_size;

    const float* x   = (const float*)d_in[0];
    const float* wg  = (const float*)d_in[1];
    const float* bg  = (const float*)d_in[2];
    const float* w1  = (const float*)d_in[3];
    const float* b1  = (const float*)d_in[4];
    const float* w2  = (const float*)d_in[5];
    const float* b2  = (const float*)d_in[6];
    const float* wzw = (const float*)d_in[7];
    const float* wzb = (const float*)d_in[8];
    const int* xlen  = (const int*)d_in[9];
    float* outp      = (float*)d_out;

    char* ws = (char*)d_ws;
    _Float16* wT   = (_Float16*)(ws);                       // 1 MiB [1024][512] f16
    _Float16* wzT  = (_Float16*)(ws + 1u * 1024 * 1024);    // 0.5 MiB [512][512] f16
    float* x1pw    = (float*)(ws +  2u * 1024 * 1024);      // 8 MiB [16384][128] h2
    float* x2tpw   = (float*)(ws + 10u * 1024 * 1024);      // 8 MiB [8][128][2048] h2
    float* xphw    = (float*)(ws + 18u * 1024 * 1024);      // 16 MiB [16384][256] h2
    float* yahw    = (float*)(ws + 34u * 1024 * 1024);      // 16 MiB [16384][256] h2

    // k0: pack weights (transposed, f16)
    hipLaunchKernelGGL(k0_tp, dim3(16, 16), dim3(256), 0, stream, wg,  wT,            512, 512);
    hipLaunchKernelGGL(k0_tp, dim3(8, 16),  dim3(256), 0, stream, w1,  wT + 512*512,  512, 256);
    hipLaunchKernelGGL(k0_tp, dim3(8, 16),  dim3(256), 0, stream, w2,  wT + 768*512,  512, 256);
    hipLaunchKernelGGL(k0_tp, dim3(16, 16), dim3(256), 0, stream, wzw, wzT,           512, 512);

    hipLaunchKernelGGL(k1_mfma, dim3(256, 4), dim3(256), 0, stream,
                       x, wT, bg, b1, b2, xphw, x1pw, x2tpw);
    hipLaunchKernelGGL(k2_attn, dim3(1024), dim3(512), 0, stream,
                       x1pw, x2tpw, xphw, xlen, yahw);
    hipLaunchKernelGGL(k3_mfma, dim3(256, 2), dim3(256), 0, stream,
                       yahw, wzT, wzb, x, outp);
}